// Round 1
// baseline (249.220 us; speedup 1.0000x reference)
//
#include <hip/hip_runtime.h>

// RhythmNetLoss: out = mean(|resnet - target|) + 100 * mean(|g - mean(g)|)
// Inputs: 3x float32 [4096,4096]. Output: 1x float32 scalar.
//
// ws layout (doubles): ws[0]=sum|r-t|, ws[1]=sum(g), ws[2]=sum|g-mean|

#define LAMBD 100.0

__device__ __forceinline__ float wave_block_reduce2(float a, float g, float* out_g) {
    // reduce across 64-lane wave
    for (int off = 32; off; off >>= 1) {
        a += __shfl_down(a, off);
        g += __shfl_down(g, off);
    }
    __shared__ float lds_a[8], lds_g[8];
    int wave = threadIdx.x >> 6;
    int nwaves = blockDim.x >> 6;
    if ((threadIdx.x & 63) == 0) { lds_a[wave] = a; lds_g[wave] = g; }
    __syncthreads();
    float ra = 0.f, rg = 0.f;
    if (threadIdx.x == 0) {
        for (int w = 0; w < nwaves; ++w) { ra += lds_a[w]; rg += lds_g[w]; }
    }
    *out_g = rg;
    return ra;
}

__global__ void __launch_bounds__(256) pass1_kernel(const float4* __restrict__ r,
                                                    const float4* __restrict__ t,
                                                    const float4* __restrict__ g,
                                                    double* __restrict__ ws, int n4) {
    float s_abs = 0.f, s_g = 0.f;
    int idx = blockIdx.x * blockDim.x + threadIdx.x;
    int stride = gridDim.x * blockDim.x;
    for (int i = idx; i < n4; i += stride) {
        float4 rv = r[i];
        float4 tv = t[i];
        float4 gv = g[i];
        s_abs += fabsf(rv.x - tv.x) + fabsf(rv.y - tv.y) +
                 fabsf(rv.z - tv.z) + fabsf(rv.w - tv.w);
        s_g += (gv.x + gv.y) + (gv.z + gv.w);
    }
    float block_g;
    float block_a = wave_block_reduce2(s_abs, s_g, &block_g);
    if (threadIdx.x == 0) {
        atomicAdd(&ws[0], (double)block_a);
        atomicAdd(&ws[1], (double)block_g);
    }
}

__global__ void __launch_bounds__(256) pass2_kernel(const float4* __restrict__ g,
                                                    double* __restrict__ ws, int n4) {
    const double inv_n = 1.0 / (double)(4096.0 * 4096.0);
    float m = (float)(ws[1] * inv_n);
    float s = 0.f;
    int idx = blockIdx.x * blockDim.x + threadIdx.x;
    int stride = gridDim.x * blockDim.x;
    for (int i = idx; i < n4; i += stride) {
        float4 gv = g[i];
        s += fabsf(gv.x - m) + fabsf(gv.y - m) +
             fabsf(gv.z - m) + fabsf(gv.w - m);
    }
    float dummy_g;
    float block_s = wave_block_reduce2(s, 0.f, &dummy_g);
    if (threadIdx.x == 0) {
        atomicAdd(&ws[2], (double)block_s);
    }
}

__global__ void finalize_kernel(const double* __restrict__ ws, float* __restrict__ out) {
    const double inv_n = 1.0 / (double)(4096.0 * 4096.0);
    double l1 = ws[0] * inv_n;
    double smooth = ws[2] * inv_n;
    out[0] = (float)(l1 + LAMBD * smooth);
}

extern "C" void kernel_launch(void* const* d_in, const int* in_sizes, int n_in,
                              void* d_out, int out_size, void* d_ws, size_t ws_size,
                              hipStream_t stream) {
    const float4* r = (const float4*)d_in[0];
    const float4* g = (const float4*)d_in[1];
    const float4* t = (const float4*)d_in[2];
    float* out = (float*)d_out;
    double* ws = (double*)d_ws;

    int n = in_sizes[0];          // 16777216
    int n4 = n >> 2;              // 4194304 float4s

    // zero the 3 double accumulators (ws is re-poisoned to 0xAA before every call)
    hipMemsetAsync(ws, 0, 3 * sizeof(double), stream);

    const int block = 256;
    int grid = 2048;              // 256 CU x 8 blocks, grid-stride the rest

    pass1_kernel<<<grid, block, 0, stream>>>(r, t, g, ws, n4);
    pass2_kernel<<<grid, block, 0, stream>>>(g, ws, n4);
    finalize_kernel<<<1, 1, 0, stream>>>(ws, out);
}

// Round 2
// 245.316 us; speedup vs baseline: 1.0159x; 1.0159x over previous
//
#include <hip/hip_runtime.h>

// RhythmNetLoss: out = mean(|resnet - target|) + 100 * mean(|g - mean(g)|)
// Inputs: 3x float32 [4096,4096]. Output: 1x float32 scalar.
//
// ws layout (doubles): ws[0]=sum|r-t|, ws[1]=sum(g), ws[2]=sum|g-mean|
//
// R1 lesson: VGPR=16 meant the compiler serialized the stream loads
// (latency-bound, 2.3 TB/s effective). Fix: 8-deep explicit unroll so all
// 24 float4 loads issue before any accumulate (MLP).

#define LAMBD 100.0
#define UNROLL 8

__device__ __forceinline__ void block_reduce2(float a, float g, float* out_a, float* out_g) {
    for (int off = 32; off; off >>= 1) {
        a += __shfl_down(a, off);
        g += __shfl_down(g, off);
    }
    __shared__ float lds_a[8], lds_g[8];
    int wave = threadIdx.x >> 6;
    int nwaves = blockDim.x >> 6;
    if ((threadIdx.x & 63) == 0) { lds_a[wave] = a; lds_g[wave] = g; }
    __syncthreads();
    float ra = 0.f, rg = 0.f;
    if (threadIdx.x == 0) {
        for (int w = 0; w < nwaves; ++w) { ra += lds_a[w]; rg += lds_g[w]; }
    }
    *out_a = ra;
    *out_g = rg;
}

__global__ void __launch_bounds__(256) pass1_kernel(const float4* __restrict__ r,
                                                    const float4* __restrict__ t,
                                                    const float4* __restrict__ g,
                                                    double* __restrict__ ws, int n4) {
    float s_abs = 0.f, s_g = 0.f;
    int idx = blockIdx.x * blockDim.x + threadIdx.x;
    int stride = gridDim.x * blockDim.x;

    int i = idx;
    for (; i + (UNROLL - 1) * stride < n4; i += UNROLL * stride) {
        float4 rv[UNROLL], tv[UNROLL], gv[UNROLL];
        // issue all loads first -> max memory-level parallelism
        #pragma unroll
        for (int u = 0; u < UNROLL; ++u) rv[u] = r[i + u * stride];
        #pragma unroll
        for (int u = 0; u < UNROLL; ++u) tv[u] = t[i + u * stride];
        #pragma unroll
        for (int u = 0; u < UNROLL; ++u) gv[u] = g[i + u * stride];
        #pragma unroll
        for (int u = 0; u < UNROLL; ++u) {
            s_abs += fabsf(rv[u].x - tv[u].x) + fabsf(rv[u].y - tv[u].y) +
                     fabsf(rv[u].z - tv[u].z) + fabsf(rv[u].w - tv[u].w);
            s_g += (gv[u].x + gv[u].y) + (gv[u].z + gv[u].w);
        }
    }
    for (; i < n4; i += stride) {
        float4 rv = r[i], tv = t[i], gv = g[i];
        s_abs += fabsf(rv.x - tv.x) + fabsf(rv.y - tv.y) +
                 fabsf(rv.z - tv.z) + fabsf(rv.w - tv.w);
        s_g += (gv.x + gv.y) + (gv.z + gv.w);
    }

    float block_a, block_g;
    block_reduce2(s_abs, s_g, &block_a, &block_g);
    if (threadIdx.x == 0) {
        atomicAdd(&ws[0], (double)block_a);
        atomicAdd(&ws[1], (double)block_g);
    }
}

__global__ void __launch_bounds__(256) pass2_kernel(const float4* __restrict__ g,
                                                    double* __restrict__ ws, int n4) {
    const double inv_n = 1.0 / (double)(4096.0 * 4096.0);
    float m = (float)(ws[1] * inv_n);
    float s = 0.f;
    int idx = blockIdx.x * blockDim.x + threadIdx.x;
    int stride = gridDim.x * blockDim.x;

    int i = idx;
    for (; i + (UNROLL - 1) * stride < n4; i += UNROLL * stride) {
        float4 gv[UNROLL];
        #pragma unroll
        for (int u = 0; u < UNROLL; ++u) gv[u] = g[i + u * stride];
        #pragma unroll
        for (int u = 0; u < UNROLL; ++u) {
            s += fabsf(gv[u].x - m) + fabsf(gv[u].y - m) +
                 fabsf(gv[u].z - m) + fabsf(gv[u].w - m);
        }
    }
    for (; i < n4; i += stride) {
        float4 gv = g[i];
        s += fabsf(gv.x - m) + fabsf(gv.y - m) +
             fabsf(gv.z - m) + fabsf(gv.w - m);
    }

    float block_s, dummy;
    block_reduce2(s, 0.f, &block_s, &dummy);
    if (threadIdx.x == 0) {
        atomicAdd(&ws[2], (double)block_s);
    }
}

__global__ void finalize_kernel(const double* __restrict__ ws, float* __restrict__ out) {
    const double inv_n = 1.0 / (double)(4096.0 * 4096.0);
    double l1 = ws[0] * inv_n;
    double smooth = ws[2] * inv_n;
    out[0] = (float)(l1 + LAMBD * smooth);
}

extern "C" void kernel_launch(void* const* d_in, const int* in_sizes, int n_in,
                              void* d_out, int out_size, void* d_ws, size_t ws_size,
                              hipStream_t stream) {
    const float4* r = (const float4*)d_in[0];
    const float4* g = (const float4*)d_in[1];
    const float4* t = (const float4*)d_in[2];
    float* out = (float*)d_out;
    double* ws = (double*)d_ws;

    int n = in_sizes[0];          // 16777216
    int n4 = n >> 2;              // 4194304 float4s

    hipMemsetAsync(ws, 0, 3 * sizeof(double), stream);

    const int block = 256;
    int grid = 2048;              // 8 blocks/CU target; 8 float4 iters/thread

    pass1_kernel<<<grid, block, 0, stream>>>(r, t, g, ws, n4);
    pass2_kernel<<<grid, block, 0, stream>>>(g, ws, n4);
    finalize_kernel<<<1, 1, 0, stream>>>(ws, out);
}

// Round 3
// 198.732 us; speedup vs baseline: 1.2540x; 1.2344x over previous
//
#include <hip/hip_runtime.h>

// RhythmNetLoss: out = mean(|r - t|) + 100 * mean(|g - mean(g)|)
// Inputs: 3x float32 [4096,4096]. Output: 1x float32 scalar.
//
// R2 lesson: MLP unroll changed nothing (88us identical) -> not latency-bound
// in-wave. New theory: serialized double-atomic tail (4096 RMWs on 2 cache
// lines from simultaneously-finishing blocks) + grid-stride DRAM pattern.
// Fix: atomic-free staging (each block owns a slot), block-contiguous tiles,
// XCD swizzle, nontemporal loads for the streams not reused (r,t).
//
// ws layout (doubles):
//   [0 .. nb)         pass1 per-block sum|r-t| partials
//   [nb .. 2nb)       pass1 per-block sum(g) partials
//   [2nb]             mean(g)   (written by mean_kernel)
//   [2nb+64 .. 3nb+64) pass2 per-block sum|g-m| partials

typedef float f32x4 __attribute__((ext_vector_type(4)));

#define LAMBD 100.0
#define BLOCK 256
#define PT 8                  // float4s per thread
#define TILE (BLOCK * PT)     // 2048 float4 = 32 KiB per stream per block

__device__ __forceinline__ void block_reduce2(float a, float g, float* oa, float* og) {
    #pragma unroll
    for (int off = 32; off; off >>= 1) {
        a += __shfl_down(a, off);
        g += __shfl_down(g, off);
    }
    __shared__ float la[4], lg[4];
    int w = threadIdx.x >> 6;
    if ((threadIdx.x & 63) == 0) { la[w] = a; lg[w] = g; }
    __syncthreads();
    if (threadIdx.x == 0) {
        float ra = 0.f, rg = 0.f;
        #pragma unroll
        for (int i = 0; i < 4; ++i) { ra += la[i]; rg += lg[i]; }
        *oa = ra; *og = rg;
    }
}

__device__ __forceinline__ int swizzle_bid(int bid, int nb) {
    if ((nb & 7) == 0) {               // bijective XCD swizzle (nb % 8 == 0)
        int nx = nb >> 3;
        return (bid & 7) * nx + (bid >> 3);
    }
    return bid;
}

__global__ void __launch_bounds__(BLOCK) pass1_kernel(const f32x4* __restrict__ r,
                                                      const f32x4* __restrict__ t,
                                                      const f32x4* __restrict__ g,
                                                      double* __restrict__ ws,
                                                      int n4, int nb) {
    int swz = swizzle_bid(blockIdx.x, nb);
    long base = (long)swz * TILE + threadIdx.x;
    float s_abs = 0.f, s_g = 0.f;

    if ((long)swz * TILE + TILE <= n4) {
        f32x4 rv[PT], tv[PT], gv[PT];
        #pragma unroll
        for (int k = 0; k < PT; ++k) rv[k] = __builtin_nontemporal_load(&r[base + k * BLOCK]);
        #pragma unroll
        for (int k = 0; k < PT; ++k) tv[k] = __builtin_nontemporal_load(&t[base + k * BLOCK]);
        #pragma unroll
        for (int k = 0; k < PT; ++k) gv[k] = g[base + k * BLOCK];
        #pragma unroll
        for (int k = 0; k < PT; ++k) {
            f32x4 d = rv[k] - tv[k];
            s_abs += fabsf(d.x) + fabsf(d.y) + fabsf(d.z) + fabsf(d.w);
            s_g   += (gv[k].x + gv[k].y) + (gv[k].z + gv[k].w);
        }
    } else {                           // generic tail (never hit for 4096^2)
        for (int k = 0; k < PT; ++k) {
            long i = base + (long)k * BLOCK;
            if (i < n4) {
                f32x4 rv = r[i], tv = t[i], gv = g[i];
                s_abs += fabsf(rv.x - tv.x) + fabsf(rv.y - tv.y) +
                         fabsf(rv.z - tv.z) + fabsf(rv.w - tv.w);
                s_g += (gv.x + gv.y) + (gv.z + gv.w);
            }
        }
    }

    float ba, bg;
    block_reduce2(s_abs, s_g, &ba, &bg);
    if (threadIdx.x == 0) {            // private slot: no atomics, no memset
        ws[swz]      = (double)ba;
        ws[nb + swz] = (double)bg;
    }
}

__global__ void __launch_bounds__(1024) mean_kernel(double* __restrict__ ws, int nb, double inv_n) {
    double v = 0.0;
    for (int i = threadIdx.x; i < nb; i += 1024) v += ws[nb + i];
    #pragma unroll
    for (int off = 32; off; off >>= 1) v += __shfl_down(v, off);
    __shared__ double lds[16];
    int w = threadIdx.x >> 6;
    if ((threadIdx.x & 63) == 0) lds[w] = v;
    __syncthreads();
    if (threadIdx.x == 0) {
        double s = 0.0;
        #pragma unroll
        for (int i = 0; i < 16; ++i) s += lds[i];
        ws[2 * nb] = s * inv_n;
    }
}

__global__ void __launch_bounds__(BLOCK) pass2_kernel(const f32x4* __restrict__ g,
                                                      double* __restrict__ ws,
                                                      int n4, int nb, int p2off) {
    float m = (float)ws[2 * nb];
    int swz = swizzle_bid(blockIdx.x, nb);
    long base = (long)swz * TILE + threadIdx.x;
    float s = 0.f;

    if ((long)swz * TILE + TILE <= n4) {
        f32x4 gv[PT];
        #pragma unroll
        for (int k = 0; k < PT; ++k) gv[k] = g[base + k * BLOCK];
        #pragma unroll
        for (int k = 0; k < PT; ++k) {
            s += fabsf(gv[k].x - m) + fabsf(gv[k].y - m) +
                 fabsf(gv[k].z - m) + fabsf(gv[k].w - m);
        }
    } else {
        for (int k = 0; k < PT; ++k) {
            long i = base + (long)k * BLOCK;
            if (i < n4) {
                f32x4 gv = g[i];
                s += fabsf(gv.x - m) + fabsf(gv.y - m) +
                     fabsf(gv.z - m) + fabsf(gv.w - m);
            }
        }
    }

    float bs, dummy;
    block_reduce2(s, 0.f, &bs, &dummy);
    if (threadIdx.x == 0) ws[p2off + swz] = (double)bs;
}

__global__ void __launch_bounds__(1024) finalize_kernel(const double* __restrict__ ws,
                                                        float* __restrict__ out,
                                                        int nb, int p2off, double inv_n) {
    double a = 0.0, s = 0.0;
    for (int i = threadIdx.x; i < nb; i += 1024) { a += ws[i]; s += ws[p2off + i]; }
    #pragma unroll
    for (int off = 32; off; off >>= 1) {
        a += __shfl_down(a, off);
        s += __shfl_down(s, off);
    }
    __shared__ double la[16], ls[16];
    int w = threadIdx.x >> 6;
    if ((threadIdx.x & 63) == 0) { la[w] = a; ls[w] = s; }
    __syncthreads();
    if (threadIdx.x == 0) {
        double ra = 0.0, rs = 0.0;
        #pragma unroll
        for (int i = 0; i < 16; ++i) { ra += la[i]; rs += ls[i]; }
        out[0] = (float)(ra * inv_n + LAMBD * (rs * inv_n));
    }
}

extern "C" void kernel_launch(void* const* d_in, const int* in_sizes, int n_in,
                              void* d_out, int out_size, void* d_ws, size_t ws_size,
                              hipStream_t stream) {
    const f32x4* r = (const f32x4*)d_in[0];
    const f32x4* g = (const f32x4*)d_in[1];
    const f32x4* t = (const f32x4*)d_in[2];
    float* out = (float*)d_out;
    double* ws = (double*)d_ws;

    int n = in_sizes[0];               // 16777216
    int n4 = n >> 2;                   // 4194304 float4s
    int nb = (n4 + TILE - 1) / TILE;   // 2048 blocks (exact fit)
    int p2off = 2 * nb + 64;
    double inv_n = 1.0 / (double)n;

    pass1_kernel<<<nb, BLOCK, 0, stream>>>(r, t, g, ws, n4, nb);
    mean_kernel<<<1, 1024, 0, stream>>>(ws, nb, inv_n);
    pass2_kernel<<<nb, BLOCK, 0, stream>>>(g, ws, n4, nb, p2off);
    finalize_kernel<<<1, 1024, 0, stream>>>(ws, out, nb, p2off, inv_n);
}